// Round 9
// baseline (566.493 us; speedup 1.0000x reference)
//
#include <hip/hip_runtime.h>
#include <hip/hip_bf16.h>
#include <stdint.h>

typedef __hip_bfloat16 bf16;
typedef __attribute__((ext_vector_type(8))) short bf16x8v;   // 8 bf16 = 4 VGPRs
typedef __attribute__((ext_vector_type(4))) float f32x4v;

#define B_   4
#define S_   8192
#define D_   1024
#define H_   16
#define DH_  64
#define M_TOT (B_ * S_)   // 32768

__device__ __forceinline__ float bf2f(bf16 x) { return __bfloat162float(x); }
__device__ __forceinline__ bf16  f2bf(float x) { return __float2bfloat16(x); }
__device__ __forceinline__ float u16tof(unsigned short u) {
  const unsigned int x = ((unsigned int)u) << 16;
  return __builtin_bit_cast(float, x);
}

// 8-wide coalesced store of one LDS row chunk (fp32 in, OutT out)
__device__ __forceinline__ void storev8(float* p, const f32x4v lo, const f32x4v hi) {
  *(f32x4v*)p = lo;
  *(f32x4v*)(p + 4) = hi;
}
__device__ __forceinline__ void storev8(bf16* p, const f32x4v lo, const f32x4v hi) {
  union { bf16 h[8]; uint4 u; } pk;
#pragma unroll
  for (int i = 0; i < 4; ++i) { pk.h[i] = f2bf(lo[i]); pk.h[4 + i] = f2bf(hi[i]); }
  *(uint4*)p = pk.u;
}

__device__ __forceinline__ void async_copy16(const void* g, void* l) {
  __builtin_amdgcn_global_load_lds(
      (const __attribute__((address_space(1))) unsigned int*)g,
      (__attribute__((address_space(3))) unsigned int*)l,
      16, 0, 0);
}

#define VMCNT(n) asm volatile("s_waitcnt vmcnt(" #n ")" ::: "memory")
__device__ __forceinline__ void barrier_() {
  asm volatile("" ::: "memory");
  __builtin_amdgcn_s_barrier();
  asm volatile("" ::: "memory");
}

// ---------------------------------------------------------------------------
// Merged preprocessing (one dispatch):
//   blocks [0,2048):     hidden_states fp32 -> bf16 (grid-stride)
//   blocks [2048,4096):  Wq / Wk transpose -> stacked [WqT;WkT] bf16
//   blocks [4096,4160):  WaqT[h][d] = Wqa[d][h] bf16
//   block  4160:         zero the pooled/sumw accumulator region (8320 floats)
// ---------------------------------------------------------------------------
__global__ __launch_bounds__(256) void prep_kernel(
    const float* __restrict__ hs, const float* __restrict__ Wq,
    const float* __restrict__ Wk, const float* __restrict__ Wqa,
    bf16* __restrict__ hs_bf, bf16* __restrict__ WqkT, bf16* __restrict__ WaqT,
    float* __restrict__ zbuf)
{
  __shared__ float tset[32][33];
  const int blk = blockIdx.x, tid = threadIdx.x;
  if (blk < 2048) {
    const int n4 = M_TOT * D_ / 4;
    for (int i = blk * 256 + tid; i < n4; i += 2048 * 256) {
      const float4 v = ((const float4*)hs)[i];
      union { bf16 h[4]; uint64_t u; } pk;
      pk.h[0] = f2bf(v.x); pk.h[1] = f2bf(v.y);
      pk.h[2] = f2bf(v.z); pk.h[3] = f2bf(v.w);
      ((uint64_t*)hs_bf)[i] = pk.u;
    }
  } else if (blk < 4096) {
    const int t = blk - 2048;
    const int mat = t >> 10, tile = t & 1023;
    const int bx = tile & 31, by = tile >> 5;
    const float* W = mat ? Wk : Wq;
    bf16* o = WqkT + (size_t)mat * 1024 * 1024;
    const int tx = tid & 31, ty0 = tid >> 5;   // 8 rows/thread-group, 4 iters
#pragma unroll
    for (int r = 0; r < 4; ++r)
      tset[ty0 + 8 * r][tx] = W[(size_t)(by * 32 + ty0 + 8 * r) * D_ + bx * 32 + tx];
    __syncthreads();
#pragma unroll
    for (int r = 0; r < 4; ++r)
      o[(size_t)(bx * 32 + ty0 + 8 * r) * D_ + by * 32 + tx] = f2bf(tset[tx][ty0 + 8 * r]);
  } else if (blk < 4160) {
    const int idx = (blk - 4096) * 256 + tid;   // < 16384
    const int d = idx & (D_ - 1), h = (idx >> 10) & 15;
    WaqT[idx] = f2bf(Wqa[d * H_ + h]);
  } else {
    for (int i = tid; i < 8320; i += 256) zbuf[i] = 0.f;
  }
}

// ---------------------------------------------------------------------------
// 256x256-tile, BK=64, 8-wave, 8-phase GEMM (round-2 schedule)
//   C[M,N] = A[M,K](lda) @ BT[N,K]^T + bias
// LDS: 2 buffers x (A[2 halves][128][64] + B[2 halves][128][64]) bf16 = 128 KiB.
// XOR swizzle byte^=((row&7)<<4) on ds_read, realized by pre-swizzling the
// per-lane GLOBAL source (global_load_lds writes linearly; rule #21).
// Counted vmcnt(4): each phase's end-barrier publishes the half-tile the next
// phase reads, with exactly 4 newer loads (2 half-tiles) left in flight.
// NEW: epilogue through LDS -> coalesced 16B stores (bf16: 4x256B segs/instr
// vs old 4x32B; fp32: 4x256B vs 4x64B). Staging [2][16][260] fp32 (stride-260
// pad: writes 2-way free, reads conflict-free - derived per-instr).
// ---------------------------------------------------------------------------
#define STAGE_A(nb, h, k0) do { \
  async_copy16(gA + (size_t)((h) * 64      ) * sA + (size_t)(k0) * 2, smem + (nb) + (h) * 16384 + ldsw); \
  async_copy16(gA + (size_t)((h) * 64 + 128) * sA + (size_t)(k0) * 2, smem + (nb) + (h) * 16384 + 8192 + ldsw); \
} while (0)

#define STAGE_B(nb, h, k0) do { \
  async_copy16(gB + (size_t)((h) * 32      ) * sB + (size_t)(k0) * 2, smem + (nb) + 32768 + (h) * 16384 + ldsw); \
  async_copy16(gB + (size_t)((h) * 32 + 128) * sB + (size_t)(k0) * 2, smem + (nb) + 32768 + (h) * 16384 + 8192 + ldsw); \
} while (0)

#define READ_A(mh) do { \
  _Pragma("unroll") for (int il = 0; il < 4; ++il) { \
    const uint8_t* p_ = Ab + (mh) * 16384 + (wr * 64 + il * 16 + l16) * 128; \
    a[il][0] = *(const bf16x8v*)(p_ + k0off); \
    a[il][1] = *(const bf16x8v*)(p_ + k1off); } \
} while (0)

#define READ_B(nh, BR) do { \
  _Pragma("unroll") for (int jl = 0; jl < 2; ++jl) { \
    const uint8_t* p_ = Bb + 32768 + (nh) * 16384 + (wc * 32 + jl * 16 + l16) * 128; \
    BR[jl][0] = *(const bf16x8v*)(p_ + k0off); \
    BR[jl][1] = *(const bf16x8v*)(p_ + k1off); } \
} while (0)

#define MFMA_Q(IOFF, JOFF, BR) do { \
  _Pragma("unroll") for (int il = 0; il < 4; ++il) \
  _Pragma("unroll") for (int jl = 0; jl < 2; ++jl) \
  _Pragma("unroll") for (int kk = 0; kk < 2; ++kk) \
    acc[(IOFF) + il][(JOFF) + jl] = __builtin_amdgcn_mfma_f32_16x16x32_bf16( \
        a[il][kk], BR[jl][kk], acc[(IOFF) + il][(JOFF) + jl], 0, 0, 0); \
} while (0)

template <typename OutT>
__global__ __launch_bounds__(512, 2) void gemm256_kernel(
    const bf16* __restrict__ A, int lda, const bf16* __restrict__ BT,
    const float* __restrict__ bias0, const float* __restrict__ bias1,
    OutT* __restrict__ C, int ldc, int M, int Ncols, int K, int perBatchB)
{
  extern __shared__ __align__(16) uint8_t smem[];

  const int ntile = Ncols >> 8;
  const int mtiles = M >> 8;
  const int xcd = blockIdx.x & 7;
  const int local = blockIdx.x >> 3;
  const int tn = local % ntile;
  const int tm = xcd * (mtiles >> 3) + local / ntile;
  const int m0 = tm << 8, n0 = tn << 8;
  const bf16* Bt = BT + (perBatchB ? (size_t)(m0 >> 13) * (size_t)Ncols * (size_t)K : 0);

  const int tid = threadIdx.x, w = tid >> 6, lane = tid & 63;
  const int quad = lane >> 4, l16 = lane & 15;
  const int wr = w >> 2, wc = w & 3;          // wave role: 2M x 4N
  const int lr = lane >> 3, ls = lane & 7;    // staging lane decomposition

  const size_t sA = (size_t)lda * 2, sB = (size_t)K * 2;
  const int srcslot = (ls ^ lr) << 4;
  const uint8_t* gA = (const uint8_t*)A  + (size_t)(m0 + 8 * w + lr) * sA + srcslot;
  const uint8_t* gB = (const uint8_t*)Bt + (size_t)(n0 + 64 * wr + 8 * wc + lr) * sB + srcslot;
  const int ldsw = w << 10;

  const int e7 = l16 & 7;
  const int k0off = (quad ^ e7) << 4;
  const int k1off = ((quad + 4) ^ e7) << 4;

  f32x4v acc[8][4] = {};
  bf16x8v a[4][2], b0[2][2], b1[2][2];

  const int NT = K >> 6;

  // prologue: stage tile0 into buf0, issue order A0,B0,B1,A1 (matches steady state)
  STAGE_A(0, 0, 0);
  STAGE_B(0, 0, 0);
  STAGE_B(0, 1, 0);
  STAGE_A(0, 1, 0);
  VMCNT(4);           // A0,B0 landed; B1,A1 still in flight
  barrier_();

  for (int t = 0; t < NT; ++t) {
    const int buf = (t & 1) << 16;
    const int nbuf = buf ^ 65536;
    const int kst = (t + 1 < NT ? t + 1 : t) << 6;   // last iter: dummy restage (dead buf)
    const uint8_t* Ab = smem + buf;
    const uint8_t* Bb = smem + buf;

    // ---- phase 0: read A0+B0 (12 ds), stage A0', MFMA q(0,0)
    READ_A(0);
    READ_B(0, b0);
    STAGE_A(nbuf, 0, kst);
    barrier_();
    __builtin_amdgcn_s_setprio(1);
    MFMA_Q(0, 0, b0);
    __builtin_amdgcn_s_setprio(0);
    VMCNT(4);         // publishes B1(t) for phase 1
    barrier_();

    // ---- phase 1: read B1 (4 ds), stage B0', MFMA q(0,1)
    READ_B(1, b1);
    STAGE_B(nbuf, 0, kst);
    barrier_();
    __builtin_amdgcn_s_setprio(1);
    MFMA_Q(0, 2, b1);
    __builtin_amdgcn_s_setprio(0);
    VMCNT(4);         // publishes A1(t) for phase 2
    barrier_();

    // ---- phase 2: read A1 (8 ds, reuse a[]), stage B1', MFMA q(1,1)
    READ_A(1);
    STAGE_B(nbuf, 1, kst);
    barrier_();
    __builtin_amdgcn_s_setprio(1);
    MFMA_Q(4, 2, b1);
    __builtin_amdgcn_s_setprio(0);
    barrier_();       // no vmcnt: phase 3 reads nothing

    // ---- phase 3: stage A1', MFMA q(1,0) (b0 held since phase 0)
    STAGE_A(nbuf, 1, kst);
    barrier_();
    __builtin_amdgcn_s_setprio(1);
    MFMA_Q(4, 0, b0);
    __builtin_amdgcn_s_setprio(0);
    VMCNT(4);         // publishes A0(t+1), B0(t+1) for next phase 0
    barrier_();
  }
  VMCNT(0);           // drain own dummy stages
  barrier_();         // join: ALL waves' dummy LDS writes landed before smem reuse

  // ---- epilogue through LDS: coalesced stores ----
  // bias per (jb): col fixed per lane across r
  float bbv[4];
#pragma unroll
  for (int jb = 0; jb < 4; ++jb) {
    const int col = n0 + wc * 64 + jb * 16 + l16;
    bbv[jb] = (col < 1024) ? (bias0 ? bias0[col] : 0.f)
                           : (bias1 ? bias1[col - 1024] : 0.f);
  }
  float* eps = (float*)smem;          // [2][16][260] fp32 = 33280 B
  const int erow = tid >> 4;          // 0..31
  const int bi = erow >> 4;           // which wr-buffer this thread stores
  const int lrow = erow & 15;
  const int c16 = (tid & 15) * 16;    // 16 cols per thread
#pragma unroll
  for (int ai = 0; ai < 8; ++ai) {
    // write: wave (wr,wc) -> buffer wr, rows quad*4+r, cols wc*64+jb*16+l16
#pragma unroll
    for (int jb = 0; jb < 4; ++jb) {
      const f32x4v v = acc[ai][jb];
#pragma unroll
      for (int r = 0; r < 4; ++r)
        eps[wr * 4160 + (quad * 4 + r) * 260 + wc * 64 + jb * 16 + l16] = v[r] + bbv[jb];
    }
    barrier_();
    // store: global row = m0 + bi*128 + ai*16 + lrow, cols n0+c16 .. +16
    OutT* cp = &C[(size_t)(m0 + bi * 128 + ai * 16 + lrow) * ldc + n0 + c16];
    const float* rp = &eps[bi * 4160 + lrow * 260 + c16];
#pragma unroll
    for (int g = 0; g < 2; ++g) {
      const f32x4v lo = *(const f32x4v*)(rp + g * 8);
      const f32x4v hi = *(const f32x4v*)(rp + g * 8 + 4);
      storev8(cp + g * 8, lo, hi);
    }
    barrier_();
  }
}

// ---------------------------------------------------------------------------
// Fused score+pool: one block = 64 rows of one batch.
// Phase A (score): e[h][s] = exp((X[row]·WaT[b][h])*scale + mask[row]) -> LDS.
//   Fixed-max softmax (M=0): scores bounded, mask only subtracts -> exp safe.
// Phase B (pool): pooled[b,c] += sum_s e[c>>6][s]*X[row0+s][c]  (X re-read is
//   L2-hot from phase A; ushort4 8B/lane coalesced); sumw[b,h] += sum_s e.
// Normalization deferred to prep_wa / transpose_scale via sumw.
// ---------------------------------------------------------------------------
__global__ __launch_bounds__(256) void score_pool_kernel(
    const bf16* __restrict__ X, int ldx, const bf16* __restrict__ WaT,
    const float* __restrict__ mask, float* __restrict__ pooled,
    float* __restrict__ sumw, float scale, int perBatchW)
{
  __shared__ float e_lds[16][65];   // +1 pad: write banks = l16 (conflict-free)
  const int tid = threadIdx.x, wave = tid >> 6, lane = tid & 63;
  const int quad = lane >> 4, l16 = lane & 15;
  const int row0 = blockIdx.x * 64;          // 64 rows, single batch (64 | S)
  const int b = row0 / S_;
  const bf16* W = WaT + (perBatchW ? (size_t)b * H_ * D_ : 0);

  // ---- phase A: scores via MFMA (wave handles 16 rows x 16 heads)
  const bf16* arow = X + (size_t)(row0 + wave * 16 + l16) * ldx;
  const bf16* brow = W + (size_t)l16 * D_;
  f32x4v acc = {};
  for (int k0 = 0; k0 < D_; k0 += 32) {
    bf16x8v av = *(const bf16x8v*)(arow + k0 + quad * 8);
    bf16x8v bv = *(const bf16x8v*)(brow + k0 + quad * 8);
    acc = __builtin_amdgcn_mfma_f32_16x16x32_bf16(av, bv, acc, 0, 0, 0);
  }
  const int srel = wave * 16 + quad * 4;     // local row of acc[0]
  const float* mp = mask + row0 + srel;      // mask is [B*S] flat; rows b-major
#pragma unroll
  for (int r = 0; r < 4; ++r)
    e_lds[l16][srel + r] = expf(acc[r] * scale + mp[r]);
  __syncthreads();

  // ---- phase B: pool. thread t owns cols 4t..4t+3 (one head: 4t..4t+3
  // never crosses a 64-boundary). e_lds read is a 16-lane broadcast.
  const int c0 = tid * 4;
  const int h = c0 >> 6;
  float p0 = 0.f, p1 = 0.f, p2 = 0.f, p3 = 0.f;
  const bf16* xb = X + (size_t)row0 * ldx + c0;
#pragma unroll 4
  for (int s = 0; s < 64; ++s) {
    const float e = e_lds[h][s];
    const ushort4 xv = *(const ushort4*)(xb + (size_t)s * ldx);
    p0 += e * u16tof(xv.x);
    p1 += e * u16tof(xv.y);
    p2 += e * u16tof(xv.z);
    p3 += e * u16tof(xv.w);
  }
  float* pd = pooled + (size_t)b * D_ + c0;
  atomicAdd(pd + 0, p0);
  atomicAdd(pd + 1, p1);
  atomicAdd(pd + 2, p2);
  atomicAdd(pd + 3, p3);
  if (tid < 16) {
    float sum = 0.f;
#pragma unroll 8
    for (int s = 0; s < 64; ++s) sum += e_lds[tid][s];
    atomicAdd(&sumw[b * H_ + tid], sum);
  }
}

// WaT[b][h][d] = Wa[d][h] * pq[b][d] * (1/sw[b][d>>6])   (pooled-q normalized here)
__global__ __launch_bounds__(256) void prep_wa_kernel(
    const float* __restrict__ Wa, const float* __restrict__ pq,
    const float* __restrict__ sw, bf16* __restrict__ out)
{
  const int idx = blockIdx.x * 256 + threadIdx.x;
  if (idx >= B_ * H_ * D_) return;
  const int d = idx & (D_ - 1);
  const int h = (idx >> 10) & 15;
  const int b = idx >> 14;
  const float inv = __frcp_rn(sw[b * H_ + (d >> 6)]);
  const float v = Wa[d * H_ + h] * pq[b * D_ + d] * inv;
  out[idx] = f2bf(v);
}

// out[b][n][k] = Wt[k][n] * (pq[b][k]/swq[b][k>>6]) * (pk[b][k]/swk[b][k>>6])
//               + (n==k)   <- residual identity-fold: mixed_q@(W+I) = mixed_q@W + mixed_q
__global__ __launch_bounds__(1024) void transpose_scale_kernel(
    const float* __restrict__ W, const float* __restrict__ pq,
    const float* __restrict__ swq, const float* __restrict__ pk,
    const float* __restrict__ swk, bf16* __restrict__ out)
{
  __shared__ float t[32][33];
  const int tx = threadIdx.x, ty = threadIdx.y;
  const int bx = blockIdx.x, by = blockIdx.y, b = blockIdx.z;
  t[ty][tx] = W[(size_t)(by * 32 + ty) * D_ + bx * 32 + tx];
  __syncthreads();
  const int n = bx * 32 + ty, k = by * 32 + tx;
  const float invq = __frcp_rn(swq[b * H_ + (k >> 6)]);
  const float invk = __frcp_rn(swk[b * H_ + (k >> 6)]);
  const float s = (pq[b * D_ + k] * invq) * (pk[b * D_ + k] * invk);
  const float v = t[tx][ty] * s + ((n == k) ? 1.f : 0.f);
  out[(size_t)b * D_ * D_ + (size_t)n * D_ + k] = f2bf(v);
}

// ---------------------------------------------------------------------------
// Dynamic-LDS opt-in (128 KiB) at .so LOAD time (graph-capture safe).
// ---------------------------------------------------------------------------
namespace {
struct LdsAttrInit {
  LdsAttrInit() {
    (void)hipFuncSetAttribute(reinterpret_cast<const void*>(&gemm256_kernel<bf16>),
                              hipFuncAttributeMaxDynamicSharedMemorySize, 131072);
    (void)hipFuncSetAttribute(reinterpret_cast<const void*>(&gemm256_kernel<float>),
                              hipFuncAttributeMaxDynamicSharedMemorySize, 131072);
  }
};
LdsAttrInit ldsAttrInit_;
}  // namespace

extern "C" void kernel_launch(void* const* d_in, const int* in_sizes, int n_in,
                              void* d_out, int out_size, void* d_ws, size_t ws_size,
                              hipStream_t stream)
{
  const float* hs   = (const float*)d_in[0];
  const float* mask = (const float*)d_in[1];
  const float* Wq   = (const float*)d_in[2];
  const float* bq   = (const float*)d_in[3];
  const float* Wqa  = (const float*)d_in[4];
  const float* Wk   = (const float*)d_in[6];
  const float* bk   = (const float*)d_in[7];
  const float* Wka  = (const float*)d_in[8];
  const float* Wt   = (const float*)d_in[10];
  const float* bt   = (const float*)d_in[11];
  float* out = (float*)d_out;

  uint8_t* w = (uint8_t*)d_ws;
  bf16*  hs_bf     = (bf16*)(w + 0);           // 67108864
  bf16*  mixed_qk  = (bf16*)(w + 67108864);    // [32768,2048] bf16 = 134217728
  bf16*  WqkT      = (bf16*)(w + 201326592);   // [2048,1024] bf16 = 4194304
  bf16*  WtTs      = (bf16*)(w + 205520896);   // 8388608 (4 batches)
  bf16*  WaqT      = (bf16*)(w + 213909504);   // 32768
  bf16*  WakTs     = (bf16*)(w + 213942272);   // 131072
  float* pq_raw    = (float*)(w + 218267648);  // 16384
  float* pk_raw    = (float*)(w + 218284032);  // 16384
  float* sumw_q    = (float*)(w + 218300416);  // 256
  float* sumw_k    = (float*)(w + 218300672);  // 256  (end ~218.3 MB)

  const bf16* mixed_q = mixed_qk;           // cols 0..1023
  const bf16* mixed_k = mixed_qk + 1024;    // cols 1024..2047
  const int LDQK = 2048;

  const float scale = 0.125f;   // 1/sqrt(DH)
  dim3 tblk(32, 32);

  // merged preprocessing: f2bf + Wq/Wk transposes + WaqT + accumulator zeroing
  prep_kernel<<<4161, 256, 0, stream>>>(hs, Wq, Wk, Wqa, hs_bf, WqkT, WaqT, pq_raw);

  // fused mixed_q|mixed_k GEMM: [32768,1024] @ [1024,2048] -> [32768,2048]
  gemm256_kernel<bf16><<<1024, 512, 131072, stream>>>(
      hs_bf, 1024, WqkT, bq, bk, mixed_qk, LDQK, M_TOT, 2048, D_, 0);

  // q attention pooling (fused score+pool; fixed-max exp, deferred norm)
  score_pool_kernel<<<512, 256, 0, stream>>>(
      mixed_q, LDQK, WaqT, mask, pq_raw, sumw_q, scale, 0);

  // qk attention pooling (normalized pooled_q folded into Wka)
  prep_wa_kernel<<<256, 256, 0, stream>>>(Wka, pq_raw, sumw_q, WakTs);
  score_pool_kernel<<<512, 256, 0, stream>>>(
      mixed_k, LDQK, WakTs, mask, pk_raw, sumw_k, scale, 1);

  // Wt scaled per batch by pooled_k = pqn*pkn, +I residual fold, transposed [N][K]
  transpose_scale_kernel<<<dim3(32, 32, 4), tblk, 0, stream>>>(
      Wt, pq_raw, sumw_q, pk_raw, sumw_k, WtTs);

  // out = mixed_q @ (WtTs + I) + bt   (fp32 output; residual folded into B)
  gemm256_kernel<float><<<512, 512, 131072, stream>>>(
      mixed_q, LDQK, WtTs, bt, nullptr, out, D_, M_TOT, D_, D_, 1);
}

// Round 10
// 552.893 us; speedup vs baseline: 1.0246x; 1.0246x over previous
//
#include <hip/hip_runtime.h>
#include <hip/hip_bf16.h>
#include <stdint.h>

typedef __hip_bfloat16 bf16;
typedef __attribute__((ext_vector_type(8))) short bf16x8v;   // 8 bf16 = 4 VGPRs
typedef __attribute__((ext_vector_type(4))) float f32x4v;

#define B_   4
#define S_   8192
#define D_   1024
#define H_   16
#define DH_  64
#define M_TOT (B_ * S_)   // 32768

__device__ __forceinline__ float bf2f(bf16 x) { return __bfloat162float(x); }
__device__ __forceinline__ bf16  f2bf(float x) { return __float2bfloat16(x); }
__device__ __forceinline__ float u16tof(unsigned short u) {
  const unsigned int x = ((unsigned int)u) << 16;
  return __builtin_bit_cast(float, x);
}

__device__ __forceinline__ void storev(float* p, float v) { *p = v; }
__device__ __forceinline__ void storev(bf16* p, float v) { *p = f2bf(v); }

__device__ __forceinline__ void async_copy16(const void* g, void* l) {
  __builtin_amdgcn_global_load_lds(
      (const __attribute__((address_space(1))) unsigned int*)g,
      (__attribute__((address_space(3))) unsigned int*)l,
      16, 0, 0);
}

#define VMCNT(n) asm volatile("s_waitcnt vmcnt(" #n ")" ::: "memory")
__device__ __forceinline__ void barrier_() {
  asm volatile("" ::: "memory");
  __builtin_amdgcn_s_barrier();
  asm volatile("" ::: "memory");
}

// ---------------------------------------------------------------------------
// Merged preprocessing (one dispatch):
//   blocks [0,2048):     hidden_states fp32 -> bf16 (grid-stride)
//   blocks [2048,4096):  Wq / Wk transpose -> stacked [WqT;WkT] bf16
//   blocks [4096,4160):  WaqT[h][d] = Wqa[d][h] bf16
//   block  4160:         zero the pooled/sumw accumulator region (8320 floats)
// ---------------------------------------------------------------------------
__global__ __launch_bounds__(256) void prep_kernel(
    const float* __restrict__ hs, const float* __restrict__ Wq,
    const float* __restrict__ Wk, const float* __restrict__ Wqa,
    bf16* __restrict__ hs_bf, bf16* __restrict__ WqkT, bf16* __restrict__ WaqT,
    float* __restrict__ zbuf)
{
  __shared__ float tset[32][33];
  const int blk = blockIdx.x, tid = threadIdx.x;
  if (blk < 2048) {
    const int n4 = M_TOT * D_ / 4;
    for (int i = blk * 256 + tid; i < n4; i += 2048 * 256) {
      const float4 v = ((const float4*)hs)[i];
      union { bf16 h[4]; uint64_t u; } pk;
      pk.h[0] = f2bf(v.x); pk.h[1] = f2bf(v.y);
      pk.h[2] = f2bf(v.z); pk.h[3] = f2bf(v.w);
      ((uint64_t*)hs_bf)[i] = pk.u;
    }
  } else if (blk < 4096) {
    const int t = blk - 2048;
    const int mat = t >> 10, tile = t & 1023;
    const int bx = tile & 31, by = tile >> 5;
    const float* W = mat ? Wk : Wq;
    bf16* o = WqkT + (size_t)mat * 1024 * 1024;
    const int tx = tid & 31, ty0 = tid >> 5;   // 8 rows/thread-group, 4 iters
#pragma unroll
    for (int r = 0; r < 4; ++r)
      tset[ty0 + 8 * r][tx] = W[(size_t)(by * 32 + ty0 + 8 * r) * D_ + bx * 32 + tx];
    __syncthreads();
#pragma unroll
    for (int r = 0; r < 4; ++r)
      o[(size_t)(bx * 32 + ty0 + 8 * r) * D_ + by * 32 + tx] = f2bf(tset[tx][ty0 + 8 * r]);
  } else if (blk < 4160) {
    const int idx = (blk - 4096) * 256 + tid;   // < 16384
    const int d = idx & (D_ - 1), h = (idx >> 10) & 15;
    WaqT[idx] = f2bf(Wqa[d * H_ + h]);
  } else {
    for (int i = tid; i < 8320; i += 256) zbuf[i] = 0.f;
  }
}

// ---------------------------------------------------------------------------
// 256x256-tile, BK=64, 8-wave, 8-phase GEMM (round-2 schedule; measured best)
//   C[M,N] = A[M,K](lda) @ BT[N,K]^T + bias
// LDS: 2 buffers x (A[2 halves][128][64] + B[2 halves][128][64]) bf16 = 128 KiB.
// XOR swizzle byte^=((row&7)<<4) on ds_read, realized by pre-swizzling the
// per-lane GLOBAL source (global_load_lds writes linearly; rule #21).
// Counted vmcnt(4): each phase's end-barrier publishes the half-tile the next
// phase reads, with exactly 4 newer loads (2 half-tiles) left in flight.
// Residual for gemm2 is identity-folded into the B matrix (WtTs + I).
// NOTE (r9 post-mortem): LDS-staged epilogue regressed (+8us, 1M bank
// conflicts) — direct 4x32B/4x64B stores kept; stores are NOT the limiter.
// Limiter model: ds_read BW (~2300cy/K-tile) co-limits with MFMA (~2480cy).
// ---------------------------------------------------------------------------
#define STAGE_A(nb, h, k0) do { \
  async_copy16(gA + (size_t)((h) * 64      ) * sA + (size_t)(k0) * 2, smem + (nb) + (h) * 16384 + ldsw); \
  async_copy16(gA + (size_t)((h) * 64 + 128) * sA + (size_t)(k0) * 2, smem + (nb) + (h) * 16384 + 8192 + ldsw); \
} while (0)

#define STAGE_B(nb, h, k0) do { \
  async_copy16(gB + (size_t)((h) * 32      ) * sB + (size_t)(k0) * 2, smem + (nb) + 32768 + (h) * 16384 + ldsw); \
  async_copy16(gB + (size_t)((h) * 32 + 128) * sB + (size_t)(k0) * 2, smem + (nb) + 32768 + (h) * 16384 + 8192 + ldsw); \
} while (0)

#define READ_A(mh) do { \
  _Pragma("unroll") for (int il = 0; il < 4; ++il) { \
    const uint8_t* p_ = Ab + (mh) * 16384 + (wr * 64 + il * 16 + l16) * 128; \
    a[il][0] = *(const bf16x8v*)(p_ + k0off); \
    a[il][1] = *(const bf16x8v*)(p_ + k1off); } \
} while (0)

#define READ_B(nh, BR) do { \
  _Pragma("unroll") for (int jl = 0; jl < 2; ++jl) { \
    const uint8_t* p_ = Bb + 32768 + (nh) * 16384 + (wc * 32 + jl * 16 + l16) * 128; \
    BR[jl][0] = *(const bf16x8v*)(p_ + k0off); \
    BR[jl][1] = *(const bf16x8v*)(p_ + k1off); } \
} while (0)

#define MFMA_Q(IOFF, JOFF, BR) do { \
  _Pragma("unroll") for (int il = 0; il < 4; ++il) \
  _Pragma("unroll") for (int jl = 0; jl < 2; ++jl) \
  _Pragma("unroll") for (int kk = 0; kk < 2; ++kk) \
    acc[(IOFF) + il][(JOFF) + jl] = __builtin_amdgcn_mfma_f32_16x16x32_bf16( \
        a[il][kk], BR[jl][kk], acc[(IOFF) + il][(JOFF) + jl], 0, 0, 0); \
} while (0)

template <typename OutT>
__global__ __launch_bounds__(512, 2) void gemm256_kernel(
    const bf16* __restrict__ A, int lda, const bf16* __restrict__ BT,
    const float* __restrict__ bias0, const float* __restrict__ bias1,
    OutT* __restrict__ C, int ldc, int M, int Ncols, int K, int perBatchB)
{
  extern __shared__ __align__(16) uint8_t smem[];

  const int ntile = Ncols >> 8;
  const int mtiles = M >> 8;
  const int xcd = blockIdx.x & 7;
  const int local = blockIdx.x >> 3;
  const int tn = local % ntile;
  const int tm = xcd * (mtiles >> 3) + local / ntile;
  const int m0 = tm << 8, n0 = tn << 8;
  const bf16* Bt = BT + (perBatchB ? (size_t)(m0 >> 13) * (size_t)Ncols * (size_t)K : 0);

  const int tid = threadIdx.x, w = tid >> 6, lane = tid & 63;
  const int quad = lane >> 4, l16 = lane & 15;
  const int wr = w >> 2, wc = w & 3;          // wave role: 2M x 4N
  const int lr = lane >> 3, ls = lane & 7;    // staging lane decomposition

  const size_t sA = (size_t)lda * 2, sB = (size_t)K * 2;
  const int srcslot = (ls ^ lr) << 4;
  const uint8_t* gA = (const uint8_t*)A  + (size_t)(m0 + 8 * w + lr) * sA + srcslot;
  const uint8_t* gB = (const uint8_t*)Bt + (size_t)(n0 + 64 * wr + 8 * wc + lr) * sB + srcslot;
  const int ldsw = w << 10;

  const int e7 = l16 & 7;
  const int k0off = (quad ^ e7) << 4;
  const int k1off = ((quad + 4) ^ e7) << 4;

  f32x4v acc[8][4] = {};
  bf16x8v a[4][2], b0[2][2], b1[2][2];

  const int NT = K >> 6;

  // prologue: stage tile0 into buf0, issue order A0,B0,B1,A1 (matches steady state)
  STAGE_A(0, 0, 0);
  STAGE_B(0, 0, 0);
  STAGE_B(0, 1, 0);
  STAGE_A(0, 1, 0);
  VMCNT(4);           // A0,B0 landed; B1,A1 still in flight
  barrier_();

  for (int t = 0; t < NT; ++t) {
    const int buf = (t & 1) << 16;
    const int nbuf = buf ^ 65536;
    const int kst = (t + 1 < NT ? t + 1 : t) << 6;   // last iter: dummy restage (dead buf)
    const uint8_t* Ab = smem + buf;
    const uint8_t* Bb = smem + buf;

    // ---- phase 0: read A0+B0 (12 ds), stage A0', MFMA q(0,0)
    READ_A(0);
    READ_B(0, b0);
    STAGE_A(nbuf, 0, kst);
    barrier_();
    __builtin_amdgcn_s_setprio(1);
    MFMA_Q(0, 0, b0);
    __builtin_amdgcn_s_setprio(0);
    VMCNT(4);         // publishes B1(t) for phase 1
    barrier_();

    // ---- phase 1: read B1 (4 ds), stage B0', MFMA q(0,1)
    READ_B(1, b1);
    STAGE_B(nbuf, 0, kst);
    barrier_();
    __builtin_amdgcn_s_setprio(1);
    MFMA_Q(0, 2, b1);
    __builtin_amdgcn_s_setprio(0);
    VMCNT(4);         // publishes A1(t) for phase 2
    barrier_();

    // ---- phase 2: read A1 (8 ds, reuse a[]), stage B1', MFMA q(1,1)
    READ_A(1);
    STAGE_B(nbuf, 1, kst);
    barrier_();
    __builtin_amdgcn_s_setprio(1);
    MFMA_Q(4, 2, b1);
    __builtin_amdgcn_s_setprio(0);
    barrier_();       // no vmcnt: phase 3 reads nothing

    // ---- phase 3: stage A1', MFMA q(1,0) (b0 held since phase 0)
    STAGE_A(nbuf, 1, kst);
    barrier_();
    __builtin_amdgcn_s_setprio(1);
    MFMA_Q(4, 0, b0);
    __builtin_amdgcn_s_setprio(0);
    VMCNT(4);         // publishes A0(t+1), B0(t+1) for next phase 0
    barrier_();
  }
  VMCNT(0);           // drain dummy stages before wave exit

  // epilogue: C/D layout col=lane&15, row=quad*4+reg  (direct stores)
#pragma unroll
  for (int ai = 0; ai < 8; ++ai) {
    const int row = m0 + wr * 128 + ai * 16 + quad * 4;
#pragma unroll
    for (int jb = 0; jb < 4; ++jb) {
      const int col = n0 + wc * 64 + jb * 16 + l16;
      const float bb = (col < 1024) ? (bias0 ? bias0[col] : 0.f)
                                    : (bias1 ? bias1[col - 1024] : 0.f);
      f32x4v v = acc[ai][jb];
#pragma unroll
      for (int r = 0; r < 4; ++r)
        storev(&C[(size_t)(row + r) * ldc + col], v[r] + bb);
    }
  }
}

// ---------------------------------------------------------------------------
// Fused score+pool: one block = 64 rows of one batch.
// Phase A (score): e[h][s] = exp((X[row]·WaT[b][h])*scale + mask[row]) -> LDS.
//   Fixed-max softmax (M=0): scores bounded, mask only subtracts -> exp safe.
// Phase B (pool): pooled[b,c] += sum_s e[c>>6][s]*X[row0+s][c]  (X re-read is
//   L2-hot from phase A; ushort4 8B/lane coalesced); sumw[b,h] += sum_s e.
// Normalization deferred to prep_wa / transpose_scale via sumw.
// ---------------------------------------------------------------------------
__global__ __launch_bounds__(256) void score_pool_kernel(
    const bf16* __restrict__ X, int ldx, const bf16* __restrict__ WaT,
    const float* __restrict__ mask, float* __restrict__ pooled,
    float* __restrict__ sumw, float scale, int perBatchW)
{
  __shared__ float e_lds[16][65];   // +1 pad: write banks = l16 (conflict-free)
  const int tid = threadIdx.x, wave = tid >> 6, lane = tid & 63;
  const int quad = lane >> 4, l16 = lane & 15;
  const int row0 = blockIdx.x * 64;          // 64 rows, single batch (64 | S)
  const int b = row0 / S_;
  const bf16* W = WaT + (perBatchW ? (size_t)b * H_ * D_ : 0);

  // ---- phase A: scores via MFMA (wave handles 16 rows x 16 heads)
  const bf16* arow = X + (size_t)(row0 + wave * 16 + l16) * ldx;
  const bf16* brow = W + (size_t)l16 * D_;
  f32x4v acc = {};
  for (int k0 = 0; k0 < D_; k0 += 32) {
    bf16x8v av = *(const bf16x8v*)(arow + k0 + quad * 8);
    bf16x8v bv = *(const bf16x8v*)(brow + k0 + quad * 8);
    acc = __builtin_amdgcn_mfma_f32_16x16x32_bf16(av, bv, acc, 0, 0, 0);
  }
  const int srel = wave * 16 + quad * 4;     // local row of acc[0]
  const float* mp = mask + row0 + srel;      // mask is [B*S] flat; rows b-major
#pragma unroll
  for (int r = 0; r < 4; ++r)
    e_lds[l16][srel + r] = __expf(acc[r] * scale + mp[r]);
  __syncthreads();

  // ---- phase B: pool. thread t owns cols 4t..4t+3 (one head: 4t..4t+3
  // never crosses a 64-boundary). e_lds read is a 16-lane broadcast.
  const int c0 = tid * 4;
  const int h = c0 >> 6;
  float p0 = 0.f, p1 = 0.f, p2 = 0.f, p3 = 0.f;
  const bf16* xb = X + (size_t)row0 * ldx + c0;
#pragma unroll 4
  for (int s = 0; s < 64; ++s) {
    const float e = e_lds[h][s];
    const ushort4 xv = *(const ushort4*)(xb + (size_t)s * ldx);
    p0 += e * u16tof(xv.x);
    p1 += e * u16tof(xv.y);
    p2 += e * u16tof(xv.z);
    p3 += e * u16tof(xv.w);
  }
  float* pd = pooled + (size_t)b * D_ + c0;
  atomicAdd(pd + 0, p0);
  atomicAdd(pd + 1, p1);
  atomicAdd(pd + 2, p2);
  atomicAdd(pd + 3, p3);
  if (tid < 16) {
    float sum = 0.f;
#pragma unroll 8
    for (int s = 0; s < 64; ++s) sum += e_lds[tid][s];
    atomicAdd(&sumw[b * H_ + tid], sum);
  }
}

// WaT[b][h][d] = Wa[d][h] * pq[b][d] * (1/sw[b][d>>6])   (pooled-q normalized here)
__global__ __launch_bounds__(256) void prep_wa_kernel(
    const float* __restrict__ Wa, const float* __restrict__ pq,
    const float* __restrict__ sw, bf16* __restrict__ out)
{
  const int idx = blockIdx.x * 256 + threadIdx.x;
  if (idx >= B_ * H_ * D_) return;
  const int d = idx & (D_ - 1);
  const int h = (idx >> 10) & 15;
  const int b = idx >> 14;
  const float inv = __frcp_rn(sw[b * H_ + (d >> 6)]);
  const float v = Wa[d * H_ + h] * pq[b * D_ + d] * inv;
  out[idx] = f2bf(v);
}

// out[b][n][k] = Wt[k][n] * (pq[b][k]/swq[b][k>>6]) * (pk[b][k]/swk[b][k>>6])
//               + (n==k)   <- residual identity-fold: mixed_q@(W+I) = mixed_q@W + mixed_q
__global__ __launch_bounds__(1024) void transpose_scale_kernel(
    const float* __restrict__ W, const float* __restrict__ pq,
    const float* __restrict__ swq, const float* __restrict__ pk,
    const float* __restrict__ swk, bf16* __restrict__ out)
{
  __shared__ float t[32][33];
  const int tx = threadIdx.x, ty = threadIdx.y;
  const int bx = blockIdx.x, by = blockIdx.y, b = blockIdx.z;
  t[ty][tx] = W[(size_t)(by * 32 + ty) * D_ + bx * 32 + tx];
  __syncthreads();
  const int n = bx * 32 + ty, k = by * 32 + tx;
  const float invq = __frcp_rn(swq[b * H_ + (k >> 6)]);
  const float invk = __frcp_rn(swk[b * H_ + (k >> 6)]);
  const float s = (pq[b * D_ + k] * invq) * (pk[b * D_ + k] * invk);
  const float v = t[tx][ty] * s + ((n == k) ? 1.f : 0.f);
  out[(size_t)b * D_ * D_ + (size_t)n * D_ + k] = f2bf(v);
}

// ---------------------------------------------------------------------------
// Dynamic-LDS opt-in (128 KiB) at .so LOAD time (graph-capture safe).
// ---------------------------------------------------------------------------
namespace {
struct LdsAttrInit {
  LdsAttrInit() {
    (void)hipFuncSetAttribute(reinterpret_cast<const void*>(&gemm256_kernel<bf16>),
                              hipFuncAttributeMaxDynamicSharedMemorySize, 131072);
    (void)hipFuncSetAttribute(reinterpret_cast<const void*>(&gemm256_kernel<float>),
                              hipFuncAttributeMaxDynamicSharedMemorySize, 131072);
  }
};
LdsAttrInit ldsAttrInit_;
}  // namespace

extern "C" void kernel_launch(void* const* d_in, const int* in_sizes, int n_in,
                              void* d_out, int out_size, void* d_ws, size_t ws_size,
                              hipStream_t stream)
{
  const float* hs   = (const float*)d_in[0];
  const float* mask = (const float*)d_in[1];
  const float* Wq   = (const float*)d_in[2];
  const float* bq   = (const float*)d_in[3];
  const float* Wqa  = (const float*)d_in[4];
  const float* Wk   = (const float*)d_in[6];
  const float* bk   = (const float*)d_in[7];
  const float* Wka  = (const float*)d_in[8];
  const float* Wt   = (const float*)d_in[10];
  const float* bt   = (const float*)d_in[11];
  float* out = (float*)d_out;

  uint8_t* w = (uint8_t*)d_ws;
  bf16*  hs_bf     = (bf16*)(w + 0);           // 67108864
  bf16*  mixed_qk  = (bf16*)(w + 67108864);    // [32768,2048] bf16 = 134217728
  bf16*  WqkT      = (bf16*)(w + 201326592);   // [2048,1024] bf16 = 4194304
  bf16*  WtTs      = (bf16*)(w + 205520896);   // 8388608 (4 batches)
  bf16*  WaqT      = (bf16*)(w + 213909504);   // 32768
  bf16*  WakTs     = (bf16*)(w + 213942272);   // 131072
  float* pq_raw    = (float*)(w + 218267648);  // 16384
  float* pk_raw    = (float*)(w + 218284032);  // 16384
  float* sumw_q    = (float*)(w + 218300416);  // 256
  float* sumw_k    = (float*)(w + 218300672);  // 256  (end ~218.3 MB)

  const bf16* mixed_q = mixed_qk;           // cols 0..1023
  const bf16* mixed_k = mixed_qk + 1024;    // cols 1024..2047
  const int LDQK = 2048;

  const float scale = 0.125f;   // 1/sqrt(DH)
  dim3 tblk(32, 32);

  // merged preprocessing: f2bf + Wq/Wk transposes + WaqT + accumulator zeroing
  prep_kernel<<<4161, 256, 0, stream>>>(hs, Wq, Wk, Wqa, hs_bf, WqkT, WaqT, pq_raw);

  // fused mixed_q|mixed_k GEMM: [32768,1024] @ [1024,2048] -> [32768,2048]
  gemm256_kernel<bf16><<<1024, 512, 131072, stream>>>(
      hs_bf, 1024, WqkT, bq, bk, mixed_qk, LDQK, M_TOT, 2048, D_, 0);

  // q attention pooling (fused score+pool; fixed-max exp, deferred norm)
  score_pool_kernel<<<512, 256, 0, stream>>>(
      mixed_q, LDQK, WaqT, mask, pq_raw, sumw_q, scale, 0);

  // qk attention pooling (normalized pooled_q folded into Wka)
  prep_wa_kernel<<<256, 256, 0, stream>>>(Wka, pq_raw, sumw_q, WakTs);
  score_pool_kernel<<<512, 256, 0, stream>>>(
      mixed_k, LDQK, WakTs, mask, pk_raw, sumw_k, scale, 1);

  // Wt scaled per batch by pooled_k = pqn*pkn, +I residual fold, transposed [N][K]
  transpose_scale_kernel<<<dim3(32, 32, 4), tblk, 0, stream>>>(
      Wt, pq_raw, sumw_q, pk_raw, sumw_k, WtTs);

  // out = mixed_q @ (WtTs + I) + bt   (fp32 output; residual folded into B)
  gemm256_kernel<float><<<512, 512, 131072, stream>>>(
      mixed_q, LDQK, WtTs, bt, nullptr, out, D_, M_TOT, D_, D_, 1);
}